// Round 12
// baseline (1384.032 us; speedup 1.0000x reference)
//
#include <hip/hip_runtime.h>

#define PI_D 3.14159265358979323846

// Layouts
//  x[l2,part]: (8192, 15, l2+1, 5, 16) fp32  n-stride = 1200*(l2+1)
//  w[l1,part]: (l1+1, 15, 5, 16, 16)  fp32
//  b[l,part]:  (1, l+1, 5, 16)        fp32
//  out[l,part]:(8192, l+1, 5, 16) concat; base = 655360*(l+1)*(l+part)
// K (4800): l2{partp{kx{t{i16}}}}; kb offsets 0,30,90,180. col (320): l{part{lr{j16}}}
// ws: G[16384] f32 @0; W'[p][col][K] bf16 @64KB; Xp3 @16MB (393MB):
//   Xp3 piece addr = ((nb*75 + kt)*64 + row%64)*640 + p*128 + (K%64)*2

typedef __attribute__((ext_vector_type(8))) short short8;
typedef __attribute__((ext_vector_type(4))) float f32x4;

struct Ptrs8 { const float* p[8]; };

__device__ __forceinline__ ushort f2bf(float x){
  uint u = __float_as_uint(x);
  return (ushort)((u + 0x7fffu + ((u>>16)&1u)) >> 16);
}

__device__ __forceinline__ double dfact(int n){ double r=1.0; for(int i=2;i<=n;++i) r*=(double)i; return r; }

__device__ double cg_coef(int j1,int m1,int j2,int m2,int j3,int m3){
  if(m1+m2!=m3) return 0.0;
  if(j3<abs(j1-j2)||j3>j1+j2) return 0.0;
  if(abs(m1)>j1||abs(m2)>j2||abs(m3)>j3) return 0.0;
  double pre = sqrt((2.0*j3+1.0)*dfact(j3+j1-j2)*dfact(j3-j1+j2)*dfact(j1+j2-j3)/dfact(j1+j2+j3+1));
  pre *= sqrt(dfact(j3+m3)*dfact(j3-m3)*dfact(j1-m1)*dfact(j1+m1)*dfact(j2-m2)*dfact(j2+m2));
  int kmin = max(0,max(j2-j3-m1,j1-j3+m2));
  int kmax = min(j1+j2-j3,min(j1-m1,j2+m2));
  double s=0.0;
  for(int k=kmin;k<=kmax;++k){
    double d = dfact(k)*dfact(j1+j2-j3-k)*dfact(j1-m1-k)*dfact(j2+m2-k)*dfact(j3-j2+m1+k)*dfact(j3-j1-m2+k);
    s += ((k&1)?-1.0:1.0)/d;
  }
  return pre*s;
}

__device__ __forceinline__ int gidx(int l,int l2,int combo,int lr,int kx,int l1,int m){
  return ((((((l*4+l2)*4+combo)*4+lr)*4+kx)*4+l1)*4+m);
}

__global__ void g_kernel(float* __restrict__ G){
  int tid = threadIdx.x;
  for(int e=tid;e<16384;e+=blockDim.x) G[e]=0.0f;
  __syncthreads();
  int trip = tid >> 4;
  int sub  = tid & 15;
  int lr = sub >> 2, m = sub & 3;
  int idx=0;
  for(int l=0;l<4;l++)for(int l1=0;l1<4;l1++){
    int lo=abs(l-l1), hi=min(3,l+l1);
    for(int l2=lo;l2<=hi;l2++){
      if(idx==trip && lr<=l && m<=l1){
        double c = 8.0*PI_D*PI_D/(2.0*l1+1.0)
                 * sqrt((2.0*l+1.0)*(2.0*l1+1.0)/(4.0*PI_D*(2.0*l2+1.0)))
                 * cg_coef(l,0,l1,0,l2,0);
        if(lr+m<=l2){
          float f = (float)(c * cg_coef(l,lr,l1,m,l2,lr+m) * ((m&1)?-1.0:1.0));
          G[gidx(l,l2,0,lr,lr+m,l1,m)] += f;
          G[gidx(l,l2,1,lr,lr+m,l1,m)] -= f;
          G[gidx(l,l2,2,lr,lr+m,l1,m)] += f;
          G[gidx(l,l2,3,lr,lr+m,l1,m)] += f;
        }
        if(m>0 && abs(lr-m)<=l2){
          if(lr-m>=0){
            float f = (float)(c * cg_coef(l,lr,l1,-m,l2,lr-m) * ((l1&1)?-1.0:1.0));
            G[gidx(l,l2,0,lr,lr-m,l1,m)] += f;
            G[gidx(l,l2,1,lr,lr-m,l1,m)] += f;
            G[gidx(l,l2,2,lr,lr-m,l1,m)] -= f;
            G[gidx(l,l2,3,lr,lr-m,l1,m)] += f;
          } else {
            float f = (float)(c * (((m-lr)&1)?-1.0:1.0) * (((l1+l2)&1)?-1.0:1.0)
                              * cg_coef(l,lr,l1,-m,l2,lr-m));
            G[gidx(l,l2,0,lr,m-lr,l1,m)] += f;
            G[gidx(l,l2,1,lr,m-lr,l1,m)] -= f;
            G[gidx(l,l2,2,lr,m-lr,l1,m)] -= f;
            G[gidx(l,l2,3,lr,m-lr,l1,m)] -= f;
          }
        }
      }
      idx++;
    }
  }
}

__device__ __forceinline__ void decode_kb(int kb,int& l2,int& partp,int& kx,int& t){
  int kbo;
  if(kb<30){l2=0;kbo=0;} else if(kb<90){l2=1;kbo=30;} else if(kb<180){l2=2;kbo=90;} else {l2=3;kbo=180;}
  int rem = kb-kbo;
  int per = (l2+1)*15;
  partp = rem/per;
  int q = rem%per;
  kx = q/15; t = q%15;
}

__device__ __forceinline__ void decode_col(int col,int& l,int& part,int& lr,int& j){
  int co;
  if(col<32){l=0;co=0;} else if(col<96){l=1;co=32;} else if(col<192){l=2;co=96;} else {l=3;co=192;}
  int cr = col-co; int per=(l+1)*16;
  part = cr/per; int q = cr%per; lr = q>>4; j = q&15;
}

// W'[p][col][K] bf16
__global__ void w_kernel(const float* __restrict__ G, Ptrs8 wp, ushort* __restrict__ W){
  long e = (long)blockIdx.x*256 + threadIdx.x;
  if(e >= 5L*320*4800) return;
  int K = (int)(e%4800); long r = e/4800; int col = (int)(r%320); int p = (int)(r/320);
  int i = K & 15; int kb = K >> 4;
  int l2,partp,kx,t; decode_kb(kb,l2,partp,kx,t);
  int l,part,lr,j; decode_col(col,l,part,lr,j);
  int combo = (part==0) ? (partp==0?0:1) : (partp==0?2:3);
  int wpart = (combo==0||combo==3)?0:1;
  int mstart = wpart?1:0;
  int woff = t*1280 + p*256 + i*16 + j;
  float acc=0.f;
  for(int l1=0;l1<4;l1++){
    const float* wptr = wp.p[l1*2+wpart];
    int gb = ((((l*4+l2)*4+combo)*4+lr)*4+kx)*16 + l1*4;
    for(int m=mstart;m<=l1;m++){
      float g = G[gb+m];
      if(g!=0.f) acc += g * wptr[m*19200 + woff];
    }
  }
  W[e] = f2bf(acc);
}

// ---------------- pack: x (fp32) -> Xp3 tile-major bf16 ----------------------
__global__ __launch_bounds__(512) void pack_kernel(Ptrs8 xp, char* __restrict__ Xp3){
  __shared__ ushort L[24000];
  const int tid = threadIdx.x;
  const int n = blockIdx.x;
  #pragma unroll
  for(int a=0;a<8;a++){
    const int l2 = a>>1, partp = a&1;
    const int kbo = (l2==0)?0:(l2==1)?30:(l2==2)?90:180;
    const int kbase = kbo + partp*15*(l2+1);
    const float* row = xp.p[a] + (long)n*1200*(l2+1);
    const int nf4 = 300*(l2+1);
    for(int u=tid; u<nf4; u+=512){
      float4 v = ((const float4*)row)[u];
      int f = u*4;
      int i = f & 15;
      int r = f >> 4;
      int p = r % 5;
      int tk = r / 5;
      int kx = tk % (l2+1);
      int t  = tk / (l2+1);
      int K = (kbase + kx*15 + t)*16 + i;
      uint2 d;
      d.x = (uint)f2bf(v.x) | ((uint)f2bf(v.y)<<16);
      d.y = (uint)f2bf(v.z) | ((uint)f2bf(v.w)<<16);
      *(uint2*)(&L[p*4800 + K]) = d;
    }
  }
  __syncthreads();
  const long rowbase = ((long)(n>>6)*75*64 + (n&63))*640;
  for(int u=tid; u<3000; u+=512){
    int kt = u/40, c = u%40;
    int p = c>>3, c8 = c&7;
    const uint4 s = *(const uint4*)(&L[p*4800 + kt*64 + c8*8]);
    *(uint4*)(Xp3 + rowbase + (long)kt*40960 + c*16) = s;
  }
}

// ---------------- GEMM: high-TLP, no LDS, no barriers ------------------------
// grid 3200 = 128nb x 5p x 5cg; block 256thr = 4 waves; wave = 64 rows x 16 cols.
// Per wave per kt: A 8 x b128 (same addrs across waves -> L1 share), B 2 x b128,
// 8 MFMA. Ping-pong depth 1; latency hidden by 16 waves/CU (launch_bounds(256,4)).
// XCD map: nb-chunked; within nb: cg, then p innermost (640B-run L2 merge).

__device__ __forceinline__ void a_ld(const char* Ab,int kt,short8* A){
  #pragma unroll
  for(int mi=0;mi<4;++mi)
    #pragma unroll
    for(int ks=0;ks<2;++ks)
      A[mi*2+ks] = *(const short8*)(Ab + (long)kt*40960 + mi*10240 + ks*64);
}

__device__ __forceinline__ void b_ld(const ushort* Wl,int kt,short8* B){
  #pragma unroll
  for(int ks=0;ks<2;++ks)
    B[ks] = *(const short8*)(Wl + kt*64 + ks*32);
}

__device__ __forceinline__ void mf(const short8* A,const short8* B,f32x4 acc[4]){
  #pragma unroll
  for(int ks=0;ks<2;++ks)
    #pragma unroll
    for(int mi=0;mi<4;++mi)
      acc[mi] = __builtin_amdgcn_mfma_f32_16x16x32_bf16(A[mi*2+ks], B[ks], acc[mi], 0,0,0);
}

__global__ __launch_bounds__(256,4) void gemm_tlp(const char* __restrict__ Xp3,
                                                  const ushort* __restrict__ Wb,
                                                  Ptrs8 bp, float* __restrict__ out){
  const int tid = threadIdx.x;
  const int lane = tid & 63;
  const int w = tid >> 6;
  // 3200 blocks: xcd = orig&7; per-XCD q in [0,400): nb_local(16) { cg(5) { p(5) } }
  int orig = blockIdx.x;
  int xcd = orig & 7, q = orig >> 3;
  const int nb = xcd*16 + q/25;
  int r = q % 25;
  const int cg = r / 5;
  const int p  = r % 5;
  const int n0 = nb*64;
  const int col16 = cg*4 + w;               // this wave's 16-col group in [0,20)
  const ushort* Wl = Wb + (long)p*320*4800 + (long)(col16*16 + (lane&15))*4800 + ((lane>>4)*8);
  const char* Ab = Xp3 + (long)nb*75*40960 + (lane&15)*640 + p*128 + (lane>>4)*16;

  f32x4 acc[4] = {};
  short8 A0[8], A1[8], B0[2], B1[2];

  a_ld(Ab, 0, A0);
  b_ld(Wl, 0, B0);
  #pragma unroll 1
  for(int kt=0; kt<74; kt+=2){
    a_ld(Ab, kt+1, A1);
    b_ld(Wl, kt+1, B1);
    mf(A0, B0, acc);
    a_ld(Ab, kt+2, A0);
    b_ld(Wl, kt+2, B0);
    mf(A1, B1, acc);
  }
  mf(A0, B0, acc);   // kt = 74

  // epilogue
  int j = lane & 15, rg = (lane>>4)*4;
  int l, part, lr;
  if(col16<2){l=0;part=col16;lr=0;}
  else if(col16<6){int c=col16-2;l=1;part=c>>1;lr=c&1;}
  else if(col16<12){int c=col16-6;l=2;part=(c>=3);lr=part?(c-3):c;}
  else {int c=col16-12;l=3;part=c>>2;lr=c&3;}
  float bv = 0.f;
  if(!(part==1 && lr==0)) bv = bp.p[l*2+part][lr*80 + p*16 + j];
  long base = 655360L*(l+1)*(l+part);
  int nst = (l+1)*80;
  long ioff = base + lr*80 + p*16 + j;
  #pragma unroll
  for(int mi=0;mi<4;++mi){
    int n = n0 + mi*16 + rg;
    #pragma unroll
    for(int rr=0;rr<4;++rr)
      out[ioff + (long)(n+rr)*nst] = acc[mi][rr] + bv;
  }
}

// ---------------- fallback GEMM (direct-from-x, R7) -------------------------
__device__ __forceinline__ void b_load10(const ushort* Wp,int w,int lane,int kt,short8* b){
  const ushort* q = Wp + (long)(w*80 + (lane&15))*4800 + kt*64 + ((lane>>4)*8);
  #pragma unroll
  for(int ks=0;ks<2;++ks)
    #pragma unroll
    for(int ni=0;ni<5;++ni)
      b[ks*5+ni] = *(const short8*)(q + (long)ni*16*4800 + ks*32);
}

__device__ __forceinline__ void a_load(const Ptrs8& xp, int p, int n0, int kt, int w, int lane, float4* v){
  int kb = kt*4 + w;
  int l2,partp,kx,t; decode_kb(kb,l2,partp,kx,t);
  const float* xb = xp.p[l2*2+partp];
  int nstr = 1200*(l2+1);
  const float* base = xb + (long)(n0 + (lane>>2))*nstr + (t*(l2+1)+kx)*80 + p*16 + (lane&3)*4;
  long step = (long)16*nstr;
  #pragma unroll
  for(int s=0;s<4;++s) v[s] = *(const float4*)(base + s*step);
}

__device__ __forceinline__ void a_store(ushort* As, int w, int lane, const float4* v){
  int rsub = lane>>2, c4 = (lane&3)*4;
  #pragma unroll
  for(int s=0;s<4;++s){
    int row = s*16 + rsub;
    int e = row*64 + ((w*16 + c4) ^ ((row&7)<<3));
    uint2 d;
    d.x = (uint)f2bf(v[s].x) | ((uint)f2bf(v[s].y)<<16);
    d.y = (uint)f2bf(v[s].z) | ((uint)f2bf(v[s].w)<<16);
    *(uint2*)(As + e) = d;
  }
}

__device__ __forceinline__ void do_mfma64(const ushort* As, int lane, const short8* b, f32x4 acc[4][5]){
  #pragma unroll
  for(int ks=0;ks<2;++ks){
    short8 af[4];
    #pragma unroll
    for(int mi=0;mi<4;++mi){
      int row = mi*16 + (lane&15);
      int e = row*64 + (((ks*32) + (lane>>4)*8) ^ ((row&7)<<3));
      af[mi] = *(const short8*)(As + e);
    }
    #pragma unroll
    for(int mi=0;mi<4;++mi)
      #pragma unroll
      for(int ni=0;ni<5;++ni)
        acc[mi][ni] = __builtin_amdgcn_mfma_f32_16x16x32_bf16(af[mi], b[ks*5+ni], acc[mi][ni], 0,0,0);
  }
}

__global__ __launch_bounds__(256,2) void gemm_direct(Ptrs8 xp, const ushort* __restrict__ Wb,
                                                     Ptrs8 bp, float* __restrict__ out){
  __shared__ ushort As[2][4096];
  const int tid = threadIdx.x;
  const int lane = tid & 63;
  const int w = tid >> 6;
  int orig = blockIdx.x;
  int x = orig & 7, q = orig >> 3;
  const int p = q % 5;
  const int nb = (q/5)*8 + x;
  const int n0 = nb*64;
  const ushort* Wp = Wb + (long)p*320*4800;

  f32x4 acc[4][5] = {};
  float4 av[4];
  short8 bfr[10];

  a_load(xp, p, n0, 0, w, lane, av);
  a_store(&As[0][0], w, lane, av);
  b_load10(Wp, w, lane, 0, bfr);
  __syncthreads();

  int buf = 0;
  #pragma unroll 1
  for(int kt=0;kt<74;++kt){
    a_load(xp, p, n0, kt+1, w, lane, av);
    do_mfma64(&As[buf][0], lane, bfr, acc);
    b_load10(Wp, w, lane, kt+1, bfr);
    a_store(&As[buf^1][0], w, lane, av);
    __syncthreads();
    buf ^= 1;
  }
  do_mfma64(&As[buf][0], lane, bfr, acc);

  int j = lane & 15, rg = (lane>>4)*4;
  #pragma unroll
  for(int ni=0;ni<5;++ni){
    int col16 = w*5 + ni;
    int l, part, lr;
    if(col16<2){l=0;part=col16;lr=0;}
    else if(col16<6){int c=col16-2;l=1;part=c>>1;lr=c&1;}
    else if(col16<12){int c=col16-6;l=2;part=(c>=3);lr=part?(c-3):c;}
    else {int c=col16-12;l=3;part=c>>2;lr=c&3;}
    float bv = 0.f;
    if(!(part==1 && lr==0)) bv = bp.p[l*2+part][lr*80 + p*16 + j];
    long base = 655360L*(l+1)*(l+part);
    int nst = (l+1)*80;
    long ioff = base + lr*80 + p*16 + j;
    #pragma unroll
    for(int mi=0;mi<4;++mi){
      int n = n0 + mi*16 + rg;
      #pragma unroll
      for(int r=0;r<4;++r)
        out[ioff + (long)(n+r)*nst] = acc[mi][ni][r] + bv;
    }
  }
}

extern "C" void kernel_launch(void* const* d_in, const int* in_sizes, int n_in,
                              void* d_out, int out_size, void* d_ws, size_t ws_size,
                              hipStream_t stream){
  Ptrs8 xp, wp, bp;
  for(int i=0;i<8;i++){
    xp.p[i] = (const float*)d_in[i];
    wp.p[i] = (const float*)d_in[8+i];
    bp.p[i] = (const float*)d_in[16+i];
  }
  float* G = (float*)d_ws;
  ushort* W = (ushort*)((char*)d_ws + 65536);
  g_kernel<<<dim3(1), dim3(576), 0, stream>>>(G);
  w_kernel<<<dim3(30000), dim3(256), 0, stream>>>(G, wp, W);
  const size_t need = 16777216ull + 393216000ull;
  if(ws_size >= need){
    char* Xp3 = (char*)d_ws + 16777216;
    pack_kernel<<<dim3(8192), dim3(512), 0, stream>>>(xp, Xp3);
    gemm_tlp<<<dim3(3200), dim3(256), 0, stream>>>(Xp3, W, bp, (float*)d_out);
  } else {
    gemm_direct<<<dim3(640), dim3(256), 0, stream>>>(xp, W, bp, (float*)d_out);
  }
}

// Round 13
// 516.237 us; speedup vs baseline: 2.6810x; 2.6810x over previous
//
#include <hip/hip_runtime.h>

#define PI_D 3.14159265358979323846

// Layouts
//  x[l2,part]: (8192, 15, l2+1, 5, 16) fp32  n-stride = 1200*(l2+1)
//  w[l1,part]: (l1+1, 15, 5, 16, 16)  fp32
//  b[l,part]:  (1, l+1, 5, 16)        fp32
//  out[l,part]:(8192, l+1, 5, 16) concat; base = 655360*(l+1)*(l+part)
// K (4800): l2{partp{kx{t{i16}}}}; kb offsets 0,30,90,180. col (320): l{part{lr{j16}}}
// ws: G @0 (64KB); W2 @64KB fragment-major bf16 (15.36MB);
//     Xp5 @16MB: [p][nb128][kt75][row64][slot8][16B] bf16 (393MB),
//     slot = c8 ^ (row&7)  (read-side LDS swizzle baked in).

typedef __attribute__((ext_vector_type(8))) short short8;
typedef __attribute__((ext_vector_type(4))) float f32x4;

struct Ptrs8 { const float* p[8]; };

__device__ __forceinline__ ushort f2bf(float x){
  uint u = __float_as_uint(x);
  return (ushort)((u + 0x7fffu + ((u>>16)&1u)) >> 16);
}

__device__ __forceinline__ double dfact(int n){ double r=1.0; for(int i=2;i<=n;++i) r*=(double)i; return r; }

__device__ double cg_coef(int j1,int m1,int j2,int m2,int j3,int m3){
  if(m1+m2!=m3) return 0.0;
  if(j3<abs(j1-j2)||j3>j1+j2) return 0.0;
  if(abs(m1)>j1||abs(m2)>j2||abs(m3)>j3) return 0.0;
  double pre = sqrt((2.0*j3+1.0)*dfact(j3+j1-j2)*dfact(j3-j1+j2)*dfact(j1+j2-j3)/dfact(j1+j2+j3+1));
  pre *= sqrt(dfact(j3+m3)*dfact(j3-m3)*dfact(j1-m1)*dfact(j1+m1)*dfact(j2-m2)*dfact(j2+m2));
  int kmin = max(0,max(j2-j3-m1,j1-j3+m2));
  int kmax = min(j1+j2-j3,min(j1-m1,j2+m2));
  double s=0.0;
  for(int k=kmin;k<=kmax;++k){
    double d = dfact(k)*dfact(j1+j2-j3-k)*dfact(j1-m1-k)*dfact(j2+m2-k)*dfact(j3-j2+m1+k)*dfact(j3-j1-m2+k);
    s += ((k&1)?-1.0:1.0)/d;
  }
  return pre*s;
}

__device__ __forceinline__ int gidx(int l,int l2,int combo,int lr,int kx,int l1,int m){
  return ((((((l*4+l2)*4+combo)*4+lr)*4+kx)*4+l1)*4+m);
}

__global__ void g_kernel(float* __restrict__ G){
  int tid = threadIdx.x;
  for(int e=tid;e<16384;e+=blockDim.x) G[e]=0.0f;
  __syncthreads();
  int trip = tid >> 4;
  int sub  = tid & 15;
  int lr = sub >> 2, m = sub & 3;
  int idx=0;
  for(int l=0;l<4;l++)for(int l1=0;l1<4;l1++){
    int lo=abs(l-l1), hi=min(3,l+l1);
    for(int l2=lo;l2<=hi;l2++){
      if(idx==trip && lr<=l && m<=l1){
        double c = 8.0*PI_D*PI_D/(2.0*l1+1.0)
                 * sqrt((2.0*l+1.0)*(2.0*l1+1.0)/(4.0*PI_D*(2.0*l2+1.0)))
                 * cg_coef(l,0,l1,0,l2,0);
        if(lr+m<=l2){
          float f = (float)(c * cg_coef(l,lr,l1,m,l2,lr+m) * ((m&1)?-1.0:1.0));
          G[gidx(l,l2,0,lr,lr+m,l1,m)] += f;
          G[gidx(l,l2,1,lr,lr+m,l1,m)] -= f;
          G[gidx(l,l2,2,lr,lr+m,l1,m)] += f;
          G[gidx(l,l2,3,lr,lr+m,l1,m)] += f;
        }
        if(m>0 && abs(lr-m)<=l2){
          if(lr-m>=0){
            float f = (float)(c * cg_coef(l,lr,l1,-m,l2,lr-m) * ((l1&1)?-1.0:1.0));
            G[gidx(l,l2,0,lr,lr-m,l1,m)] += f;
            G[gidx(l,l2,1,lr,lr-m,l1,m)] += f;
            G[gidx(l,l2,2,lr,lr-m,l1,m)] -= f;
            G[gidx(l,l2,3,lr,lr-m,l1,m)] += f;
          } else {
            float f = (float)(c * (((m-lr)&1)?-1.0:1.0) * (((l1+l2)&1)?-1.0:1.0)
                              * cg_coef(l,lr,l1,-m,l2,lr-m));
            G[gidx(l,l2,0,lr,m-lr,l1,m)] += f;
            G[gidx(l,l2,1,lr,m-lr,l1,m)] -= f;
            G[gidx(l,l2,2,lr,m-lr,l1,m)] -= f;
            G[gidx(l,l2,3,lr,m-lr,l1,m)] -= f;
          }
        }
      }
      idx++;
    }
  }
}

__device__ __forceinline__ void decode_kb(int kb,int& l2,int& partp,int& kx,int& t){
  int kbo;
  if(kb<30){l2=0;kbo=0;} else if(kb<90){l2=1;kbo=30;} else if(kb<180){l2=2;kbo=90;} else {l2=3;kbo=180;}
  int rem = kb-kbo;
  int per = (l2+1)*15;
  partp = rem/per;
  int q = rem%per;
  kx = q/15; t = q%15;
}

__device__ __forceinline__ void decode_col(int col,int& l,int& part,int& lr,int& j){
  int co;
  if(col<32){l=0;co=0;} else if(col<96){l=1;co=32;} else if(col<192){l=2;co=96;} else {l=3;co=192;}
  int cr = col-co; int per=(l+1)*16;
  part = cr/per; int q = cr%per; lr = q>>4; j = q&15;
}

// W2: fragment-major bf16. e = (((p*20+cw)*75+kt)*2+ks)*512 + lane*8 + b8
// value = folded-W at (p, col=cw*16+(lane&15), K=kt*64+ks*32+(lane>>4)*8+b8)
__global__ void w2_kernel(const float* __restrict__ G, Ptrs8 wp, ushort* __restrict__ W2){
  long e = (long)blockIdx.x*256 + threadIdx.x;
  if(e >= 7680000L) return;
  int b8 = (int)(e & 7);
  int ln = (int)((e>>3) & 63);
  int ks = (int)((e>>9) & 1);
  int kt = (int)((e>>10) % 75);
  long rr = (e>>10) / 75;            // p*20+cw
  int cw = (int)(rr % 20);
  int p  = (int)(rr / 20);
  int col = cw*16 + (ln&15);
  int K = kt*64 + ks*32 + ((ln>>4)<<3) + b8;
  int i = K & 15; int kb = K >> 4;
  int l2,partp,kx,t; decode_kb(kb,l2,partp,kx,t);
  int l,part,lr,j; decode_col(col,l,part,lr,j);
  int combo = (part==0) ? (partp==0?0:1) : (partp==0?2:3);
  int wpart = (combo==0||combo==3)?0:1;
  int mstart = wpart?1:0;
  int woff = t*1280 + p*256 + i*16 + j;
  float acc=0.f;
  for(int l1=0;l1<4;l1++){
    const float* wptr = wp.p[l1*2+wpart];
    int gb = ((((l*4+l2)*4+combo)*4+lr)*4+kx)*16 + l1*4;
    for(int m=mstart;m<=l1;m++){
      float g = G[gb+m];
      if(g!=0.f) acc += g * wptr[m*19200 + woff];
    }
  }
  W2[e] = f2bf(acc);
}

// ---------------- pack: x (fp32) -> Xp5 bf16, LDS-swizzle baked --------------
// One block per n-row (XCD-chunked n so tile pieces merge in one L2).
// Reads fully contiguous; writes 128-B runs (8x16B permuted within run).
__global__ __launch_bounds__(512) void pack_kernel(Ptrs8 xp, char* __restrict__ Xp5){
  __shared__ ushort L[24000];
  const int tid = threadIdx.x;
  const int n = (blockIdx.x & 7)*1024 + (blockIdx.x >> 3);
  #pragma unroll
  for(int a=0;a<8;a++){
    const int l2 = a>>1, partp = a&1;
    const int kbo = (l2==0)?0:(l2==1)?30:(l2==2)?90:180;
    const int kbase = kbo + partp*15*(l2+1);
    const float* row = xp.p[a] + (long)n*1200*(l2+1);
    const int nf4 = 300*(l2+1);
    for(int u=tid; u<nf4; u+=512){
      float4 v = ((const float4*)row)[u];
      int f = u*4;
      int i = f & 15;
      int r = f >> 4;
      int p = r % 5;
      int tk = r / 5;
      int kx = tk % (l2+1);
      int t  = tk / (l2+1);
      int K = (kbase + kx*15 + t)*16 + i;
      uint2 d;
      d.x = (uint)f2bf(v.x) | ((uint)f2bf(v.y)<<16);
      d.y = (uint)f2bf(v.z) | ((uint)f2bf(v.w)<<16);
      *(uint2*)(&L[p*4800 + K]) = d;
    }
  }
  __syncthreads();
  // writeout: Xp5 tile(p, nb=n>>6, kt): row (n&63), slot = c8 ^ (n&7)
  const int nb = n>>6, rloc = n&63, sw = n&7;
  for(int u=tid; u<3000; u+=512){
    int kt = u/40, rem = u%40;
    int p = rem>>3, c8 = rem&7;
    const uint4 s = *(const uint4*)(&L[p*4800 + kt*64 + c8*8]);
    long off = ((long)(p*128 + nb)*75 + kt)*8192 + rloc*128 + ((c8 ^ sw)<<4);
    *(uint4*)(Xp5 + off) = s;
  }
}

// ---------------- GEMM: all loads coalesced (R2 schedule) --------------------
// 64r x 320c tile, 4 waves (80c each), grid 640 (p-chunked per XCD).
// A: Xp5 tile 8KB -> 2 coalesced b128/thread -> linear ds_write; fragment
// ds_read with baked XOR swizzle (2-way = free). B: 1-KB contiguous fragment
// loads from W2 (L2/L3-resident), distance-1. __syncthreads per iter.

__device__ __forceinline__ void b_load2(const ushort* Wt,int lane,int kt,short8* b){
  #pragma unroll
  for(int ni=0;ni<5;++ni)
    #pragma unroll
    for(int ks=0;ks<2;++ks)
      b[ks*5+ni] = *(const short8*)(Wt + (long)ni*76800 + kt*1024 + ks*512 + lane*8);
}

__device__ __forceinline__ void do_mfma_f(const ushort* A,int lane,const short8* b,f32x4 acc[4][5]){
  #pragma unroll
  for(int ks=0;ks<2;++ks){
    short8 af[4];
    #pragma unroll
    for(int mi=0;mi<4;++mi){
      int row = mi*16 + (lane&15);
      int kc = ks*4 + (lane>>4);
      af[mi] = *(const short8*)(A + row*64 + ((kc ^ (row&7))<<3));
    }
    #pragma unroll
    for(int mi=0;mi<4;++mi)
      #pragma unroll
      for(int ni=0;ni<5;++ni)
        acc[mi][ni] = __builtin_amdgcn_mfma_f32_16x16x32_bf16(af[mi], b[ks*5+ni], acc[mi][ni], 0,0,0);
  }
}

__global__ __launch_bounds__(256,2) void gemm_f(const char* __restrict__ Xp5,
                                                const ushort* __restrict__ W2,
                                                Ptrs8 bp, float* __restrict__ out){
  __shared__ ushort As[2][4096];
  const int tid = threadIdx.x;
  const int lane = tid & 63;
  const int w = tid >> 6;
  int orig = blockIdx.x;
  int xcd = orig & 7, q = orig >> 3;      // q in [0,80)
  const int p = q / 16;
  const int nb = xcd*16 + (q % 16);
  const int n0 = nb*64;
  const char* At = Xp5 + ((long)(p*128 + nb)*75)*8192;
  const ushort* Wt = W2 + (long)(p*20 + w*5)*76800;

  f32x4 acc[4][5] = {};
  uint4 sA0, sA1;
  short8 bfr[10];

  // prologue: tile0 -> LDS (coalesced), B(0)
  sA0 = *(const uint4*)(At + tid*16);
  sA1 = *(const uint4*)(At + 4096 + tid*16);
  *(uint4*)(&As[0][tid*8]) = sA0;
  *(uint4*)(&As[0][2048 + tid*8]) = sA1;
  b_load2(Wt, lane, 0, bfr);
  __syncthreads();

  int buf = 0;
  #pragma unroll 1
  for(int kt=0;kt<74;++kt){
    sA0 = *(const uint4*)(At + (kt+1)*8192 + tid*16);       // A(kt+1), coalesced
    sA1 = *(const uint4*)(At + (kt+1)*8192 + 4096 + tid*16);
    do_mfma_f(&As[buf][0], lane, bfr, acc);                 // compute tile kt
    b_load2(Wt, lane, kt+1, bfr);                           // B(kt+1), coalesced
    *(uint4*)(&As[buf^1][tid*8]) = sA0;
    *(uint4*)(&As[buf^1][2048 + tid*8]) = sA1;
    __syncthreads();
    buf ^= 1;
  }
  do_mfma_f(&As[buf][0], lane, bfr, acc);

  // epilogue
  int j = lane & 15, rg = (lane>>4)*4;
  #pragma unroll
  for(int ni=0;ni<5;++ni){
    int col16 = w*5 + ni;
    int l, part, lr;
    if(col16<2){l=0;part=col16;lr=0;}
    else if(col16<6){int c=col16-2;l=1;part=c>>1;lr=c&1;}
    else if(col16<12){int c=col16-6;l=2;part=(c>=3);lr=part?(c-3):c;}
    else {int c=col16-12;l=3;part=c>>2;lr=c&3;}
    float bv = 0.f;
    if(!(part==1 && lr==0)) bv = bp.p[l*2+part][lr*80 + p*16 + j];
    long base = 655360L*(l+1)*(l+part);
    int nst = (l+1)*80;
    long ioff = base + lr*80 + p*16 + j;
    #pragma unroll
    for(int mi=0;mi<4;++mi){
      int n = n0 + mi*16 + rg;
      #pragma unroll
      for(int r=0;r<4;++r)
        out[ioff + (long)(n+r)*nst] = acc[mi][ni][r] + bv;
    }
  }
}

// ---------------- fallback (direct-from-x, R7 path, uses W2 via gather) ------
// Only used if ws too small; recompute W in old layout is gone, so fallback
// loads B from W2 fragment layout with matching indexing.
__device__ __forceinline__ void a_load(const Ptrs8& xp, int p, int n0, int kt, int w, int lane, float4* v){
  int kb = kt*4 + w;
  int l2,partp,kx,t; decode_kb(kb,l2,partp,kx,t);
  const float* xb = xp.p[l2*2+partp];
  int nstr = 1200*(l2+1);
  const float* base = xb + (long)(n0 + (lane>>2))*nstr + (t*(l2+1)+kx)*80 + p*16 + (lane&3)*4;
  long step = (long)16*nstr;
  #pragma unroll
  for(int s=0;s<4;++s) v[s] = *(const float4*)(base + s*step);
}

__device__ __forceinline__ void a_store(ushort* As, int w, int lane, const float4* v){
  int rsub = lane>>2, c4 = (lane&3)*4;
  #pragma unroll
  for(int s=0;s<4;++s){
    int row = s*16 + rsub;
    int e = row*64 + ((w*16 + c4) ^ ((row&7)<<3));
    uint2 d;
    d.x = (uint)f2bf(v[s].x) | ((uint)f2bf(v[s].y)<<16);
    d.y = (uint)f2bf(v[s].z) | ((uint)f2bf(v[s].w)<<16);
    *(uint2*)(As + e) = d;
  }
}

__device__ __forceinline__ void do_mfma64(const ushort* As, int lane, const short8* b, f32x4 acc[4][5]){
  #pragma unroll
  for(int ks=0;ks<2;++ks){
    short8 af[4];
    #pragma unroll
    for(int mi=0;mi<4;++mi){
      int row = mi*16 + (lane&15);
      int e = row*64 + (((ks*32) + (lane>>4)*8) ^ ((row&7)<<3));
      af[mi] = *(const short8*)(As + e);
    }
    #pragma unroll
    for(int mi=0;mi<4;++mi)
      #pragma unroll
      for(int ni=0;ni<5;++ni)
        acc[mi][ni] = __builtin_amdgcn_mfma_f32_16x16x32_bf16(af[mi], b[ks*5+ni], acc[mi][ni], 0,0,0);
  }
}

__global__ __launch_bounds__(256,2) void gemm_direct(Ptrs8 xp, const ushort* __restrict__ W2,
                                                     Ptrs8 bp, float* __restrict__ out){
  __shared__ ushort As[2][4096];
  const int tid = threadIdx.x;
  const int lane = tid & 63;
  const int w = tid >> 6;
  int orig = blockIdx.x;
  int x = orig & 7, q = orig >> 3;
  const int p = q % 5;
  const int nb = (q/5)*8 + x;
  const int n0 = nb*64;
  const ushort* Wt = W2 + (long)(p*20 + w*5)*76800;

  f32x4 acc[4][5] = {};
  float4 av[4];
  short8 bfr[10];

  a_load(xp, p, n0, 0, w, lane, av);
  a_store(&As[0][0], w, lane, av);
  b_load2(Wt, lane, 0, bfr);
  __syncthreads();

  int buf = 0;
  #pragma unroll 1
  for(int kt=0;kt<74;++kt){
    a_load(xp, p, n0, kt+1, w, lane, av);
    do_mfma64(&As[buf][0], lane, bfr, acc);
    b_load2(Wt, lane, kt+1, bfr);
    a_store(&As[buf^1][0], w, lane, av);
    __syncthreads();
    buf ^= 1;
  }
  do_mfma64(&As[buf][0], lane, bfr, acc);

  int j = lane & 15, rg = (lane>>4)*4;
  #pragma unroll
  for(int ni=0;ni<5;++ni){
    int col16 = w*5 + ni;
    int l, part, lr;
    if(col16<2){l=0;part=col16;lr=0;}
    else if(col16<6){int c=col16-2;l=1;part=c>>1;lr=c&1;}
    else if(col16<12){int c=col16-6;l=2;part=(c>=3);lr=part?(c-3):c;}
    else {int c=col16-12;l=3;part=c>>2;lr=c&3;}
    float bv = 0.f;
    if(!(part==1 && lr==0)) bv = bp.p[l*2+part][lr*80 + p*16 + j];
    long base = 655360L*(l+1)*(l+part);
    int nst = (l+1)*80;
    long ioff = base + lr*80 + p*16 + j;
    #pragma unroll
    for(int mi=0;mi<4;++mi){
      int n = n0 + mi*16 + rg;
      #pragma unroll
      for(int r=0;r<4;++r)
        out[ioff + (long)(n+r)*nst] = acc[mi][ni][r] + bv;
    }
  }
}

extern "C" void kernel_launch(void* const* d_in, const int* in_sizes, int n_in,
                              void* d_out, int out_size, void* d_ws, size_t ws_size,
                              hipStream_t stream){
  Ptrs8 xp, wp, bp;
  for(int i=0;i<8;i++){
    xp.p[i] = (const float*)d_in[i];
    wp.p[i] = (const float*)d_in[8+i];
    bp.p[i] = (const float*)d_in[16+i];
  }
  float* G = (float*)d_ws;
  ushort* W2 = (ushort*)((char*)d_ws + 65536);
  g_kernel<<<dim3(1), dim3(576), 0, stream>>>(G);
  w2_kernel<<<dim3(30000), dim3(256), 0, stream>>>(G, wp, W2);
  const size_t need = 16777216ull + 393216000ull;
  if(ws_size >= need){
    char* Xp5 = (char*)d_ws + 16777216;
    pack_kernel<<<dim3(8192), dim3(512), 0, stream>>>(xp, Xp5);
    gemm_f<<<dim3(640), dim3(256), 0, stream>>>(Xp5, W2, bp, (float*)d_out);
  } else {
    gemm_direct<<<dim3(640), dim3(256), 0, stream>>>(xp, W2, bp, (float*)d_out);
  }
}